// Round 8
// baseline (11287.415 us; speedup 1.0000x reference)
//
#include <hip/hip_runtime.h>

#define NUM_ITERS 15
#define BB 2
#define NN 2048
#define QQ 256

// ---------------------------------------------------------------------------
// Exact replication of numpy float32 semantics:
//  - no FMA contraction anywhere (pragma clang fp contract(off))
//  - einsum: sequential ascending-k, round(mul) then round(add), fp32
//  - sum(axis=1): sequential ascending-n, fp32
//  - sum(axis=-1): numpy pairwise_sum tree (128-blocks, 8 accumulators)
//  - e_eff = acc / n_e  (true division, not reciprocal-multiply)
//  - every reference array boundary rounds to fp32 (state stored fp32)
// ---------------------------------------------------------------------------

// numpy pairwise block for n=128 (8 accumulators + fixed combine tree)
__device__ float np_pw128(const float* a)
{
#pragma clang fp contract(off)
    float r0 = a[0], r1 = a[1], r2 = a[2], r3 = a[3];
    float r4 = a[4], r5 = a[5], r6 = a[6], r7 = a[7];
    for (int i = 8; i < 128; i += 8) {
        r0 += a[i + 0]; r1 += a[i + 1]; r2 += a[i + 2]; r3 += a[i + 3];
        r4 += a[i + 4]; r5 += a[i + 5]; r6 += a[i + 6]; r7 += a[i + 7];
    }
    return ((r0 + r1) + (r2 + r3)) + ((r4 + r5) + (r6 + r7));
}

// numpy pairwise_sum for n=256: split 128+128
__device__ float np_sum256(const float* a)
{
#pragma clang fp contract(off)
    return np_pw128(a) + np_pw128(a + 128);
}

// ---------------------------------------------------------------------------
// Column sums (fp32, sequential ascending n — matches np.sum(axis=1)):
// sums[b][m] = sum_n thr(adj[b][n][m]) * act[b][n];  act==null -> ones.
// ---------------------------------------------------------------------------
__global__ __launch_bounds__(256) void colsum_kernel(
    const float* __restrict__ adj, const float* act,
    float* __restrict__ sum_e, float* __restrict__ sum_i)
{
#pragma clang fp contract(off)
    const int b = (int)blockIdx.z;
    const int m = (int)blockIdx.x * 256 + (int)threadIdx.x;
    const float* src = adj + (size_t)b * NN * NN;
    const float* ab = (act != 0) ? (act + (size_t)b * NN) : (const float*)0;
    float se = 0.0f;
    float si = 0.0f;
    for (int n = 0; n < NN; ++n) {
        float x = src[(size_t)n * NN + m];
        float e = (x > 0.5f) ? x : 0.0f;
        float v = 1.0f - x;
        float iv = (v > 0.5f) ? v : 0.0f;
        if (ab != 0) {
            float av = ab[n];
            e = e * av;      // Ae rounds here in np (exact for 0/1 masks)
            iv = iv * av;
        }
        se = se + e;
        si = si + iv;
    }
    sum_e[b * NN + m] = se;
    sum_i[b * NN + m] = si;
}

// ---------------------------------------------------------------------------
// Fused thresholded GEMM, np-fp32-exact:
//   C[m][q] = sum_k (thr(adj[k][m]) * act[k]) * hsrc[k][q]  (ascending k,
//             round each product, round each add, no FMA)
//   mode 0: dst[m][q] = h_old[m][q] + (C[m][q] / max(sum[m],1))
//   mode 1: dst[m][q] =               C[m][q] / max(sum[m],1)
// Block 256, tile M=64 x Q=64, K-step 16, thread computes 4x4.
// ---------------------------------------------------------------------------
__global__ __launch_bounds__(256) void gemm_fused(
    const float* __restrict__ adj,
    const float* __restrict__ hsrc,
    const float* act,
    const float* __restrict__ sums,
    const float* h_old,
    float* __restrict__ dst,
    int mode)
{
#pragma clang fp contract(off)
    __shared__ float Ws[16][68];
    __shared__ float Hs[16][68];

    const int b  = (int)blockIdx.z;
    const int m0 = (int)blockIdx.x * 64;
    const int q0 = (int)blockIdx.y * 64;
    const int tid = (int)threadIdx.x;
    const int tm = tid & 15;
    const int tq = tid >> 4;

    const float* adjb = adj + (size_t)b * NN * NN;
    const float* hb   = hsrc + (size_t)b * NN * QQ;
    const float* ab   = (act != 0) ? (act + (size_t)b * NN) : (const float*)0;

    float acc[4][4];
    for (int i = 0; i < 4; ++i)
        for (int j = 0; j < 4; ++j)
            acc[i][j] = 0.0f;

    for (int k0 = 0; k0 < NN; k0 += 16) {
        for (int i = 0; i < 4; ++i) {
            int idx = tid + 256 * i;      // 0..1023
            int kk = idx >> 6;            // 0..15
            int mm = idx & 63;            // 0..63
            float x = adjb[(size_t)(k0 + kk) * NN + m0 + mm];
            float wgt;
            if (mode == 0) {
                wgt = (x > 0.5f) ? x : 0.0f;
            } else {
                float v = 1.0f - x;
                wgt = (v > 0.5f) ? v : 0.0f;
            }
            if (ab != 0) wgt = wgt * ab[k0 + kk];   // Ae = adj_e * act (np rounding)
            Ws[kk][mm] = wgt;
            Hs[kk][mm] = hb[(size_t)(k0 + kk) * QQ + q0 + mm];  // pure h
        }
        __syncthreads();
        for (int kk = 0; kk < 16; ++kk) {
            float a0 = Ws[kk][tm * 4 + 0];
            float a1 = Ws[kk][tm * 4 + 1];
            float a2 = Ws[kk][tm * 4 + 2];
            float a3 = Ws[kk][tm * 4 + 3];
            float b0 = Hs[kk][tq * 4 + 0];
            float b1 = Hs[kk][tq * 4 + 1];
            float b2 = Hs[kk][tq * 4 + 2];
            float b3 = Hs[kk][tq * 4 + 3];
            // round(mul) then round(add); contract(off) forbids FMA fusion
            acc[0][0] = acc[0][0] + a0 * b0; acc[0][1] = acc[0][1] + a0 * b1;
            acc[0][2] = acc[0][2] + a0 * b2; acc[0][3] = acc[0][3] + a0 * b3;
            acc[1][0] = acc[1][0] + a1 * b0; acc[1][1] = acc[1][1] + a1 * b1;
            acc[1][2] = acc[1][2] + a1 * b2; acc[1][3] = acc[1][3] + a1 * b3;
            acc[2][0] = acc[2][0] + a2 * b0; acc[2][1] = acc[2][1] + a2 * b1;
            acc[2][2] = acc[2][2] + a2 * b2; acc[2][3] = acc[2][3] + a2 * b3;
            acc[3][0] = acc[3][0] + a3 * b0; acc[3][1] = acc[3][1] + a3 * b1;
            acc[3][2] = acc[3][2] + a3 * b2; acc[3][3] = acc[3][3] + a3 * b3;
        }
        __syncthreads();
    }

    for (int i = 0; i < 4; ++i) {
        int row = m0 + tm * 4 + i;
        float s = sums[b * NN + row];
        if (s < 1.0f) s = 1.0f;           // np.maximum(sum, 1.0)
        for (int j = 0; j < 4; ++j) {
            int col = q0 + tq * 4 + j;
            size_t gi = ((size_t)b * NN + row) * QQ + col;
            float v = acc[i][j] / s;      // true division (np divide)
            if (mode == 0) {
                dst[gi] = h_old[gi] + v;
            } else {
                dst[gi] = v;
            }
        }
    }
}

// ---------------------------------------------------------------------------
// Projection + relu + L2-normalize, np-fp32-exact, in place on h_io.
// Row sums over q use numpy's pairwise tree (serial on thread 0).
// Block = one row m (256 threads = q). Grid (NN, BB).
// ---------------------------------------------------------------------------
__global__ __launch_bounds__(256) void project_kernel(
    float* h_io, const float* __restrict__ ieff)
{
#pragma clang fp contract(off)
    __shared__ float sp[256];
    __shared__ float sq[256];
    __shared__ float sc[2];
    const int b = (int)blockIdx.y;
    const int m = (int)blockIdx.x;
    const int t = (int)threadIdx.x;

    size_t gi = ((size_t)b * NN + m) * QQ + t;
    float hv = h_io[gi];
    float ie = ieff[gi];

    sp[t] = hv * ie;   // (h * i_eff) rounds elementwise in np
    sq[t] = ie * ie;   // (i_eff * i_eff)
    __syncthreads();
    if (t == 0) {
        float dot = np_sum256(sp);
        float un  = np_sum256(sq);
        sc[0] = dot / (un + 1e-12f);
    }
    __syncthreads();
    float c = sc[0];
    float tmp = c * ie;              // rounds
    float h2 = hv - tmp;             // rounds
    float r = (h2 > 0.0f) ? h2 : 0.0f;   // relu = maximum(x, 0)
    sp[t] = r * r;
    __syncthreads();
    if (t == 0) {
        float nn = np_sum256(sp);
        float den = (float)sqrt((double)nn);   // correctly-rounded fp32 sqrt
        if (den < 1e-8f) den = 1e-8f;          // np.maximum(n, 1e-8)
        sc[1] = den;
    }
    __syncthreads();
    float val = r / sc[1];           // true division per element
    h_io[gi] = val;
}

// ---------------------------------------------------------------------------
// Pipeline: fp32 throughout (matching np-fp32 golden). d_out slice[it] holds
// h after iteration it and serves as the state chain.
//   it = 0: act = activated (identified by size), masked colsums.
//   it >= 1: act = ones via act == nullptr.
// ws: ieff (4 MB) + 4 colsum vectors.
// ---------------------------------------------------------------------------
extern "C" void kernel_launch(void* const* d_in, const int* in_sizes, int n_in,
                              void* d_out, int out_size, void* d_ws, size_t ws_size,
                              hipStream_t stream)
{
    const float* h0     = 0;
    const float* adj    = 0;
    const float* act_in = 0;
    for (int i = 0; i < n_in; ++i) {
        if (in_sizes[i] == BB * NN * QQ)      h0     = (const float*)d_in[i];
        else if (in_sizes[i] == BB * NN * NN) adj    = (const float*)d_in[i];
        else if (in_sizes[i] == BB * NN)      act_in = (const float*)d_in[i];
    }
    float* out = (float*)d_out;

    char* ws = (char*)d_ws;
    size_t off = 0;
    float* ieff   = (float*)(ws + off); off += (size_t)BB * NN * QQ * 4;  // 4 MB
    float* sum_e0 = (float*)(ws + off); off += (size_t)BB * NN * 4;
    float* sum_i0 = (float*)(ws + off); off += (size_t)BB * NN * 4;
    float* sum_e1 = (float*)(ws + off); off += (size_t)BB * NN * 4;
    float* sum_i1 = (float*)(ws + off); off += (size_t)BB * NN * 4;

    const size_t slice_sz = (size_t)BB * NN * QQ;

    colsum_kernel<<<dim3(NN / 256, 1, BB), 256, 0, stream>>>(
        adj, act_in, sum_e0, sum_i0);
    colsum_kernel<<<dim3(NN / 256, 1, BB), 256, 0, stream>>>(
        adj, (const float*)0, sum_e1, sum_i1);

    for (int it = 0; it < NUM_ITERS; ++it) {
        const float* act = (it == 0) ? act_in : (const float*)0;
        const float* se  = (it == 0) ? sum_e0 : sum_e1;
        const float* si  = (it == 0) ? sum_i0 : sum_i1;
        const float* h_prev = (it == 0) ? h0 : (out + (size_t)(it - 1) * slice_sz);
        float* h_cur = out + (size_t)it * slice_sz;

        // h_cur = h_prev + e_eff   (excite)
        gemm_fused<<<dim3(NN / 64, QQ / 64, BB), 256, 0, stream>>>(
            adj, h_prev, act, se, h_prev, h_cur, 0);
        // ieff from updated h     (inhibit)
        gemm_fused<<<dim3(NN / 64, QQ / 64, BB), 256, 0, stream>>>(
            adj, h_cur, act, si, (const float*)0, ieff, 1);
        // projection + relu + normalize (np-exact), in place
        project_kernel<<<dim3(NN, BB), 256, 0, stream>>>(h_cur, ieff);
    }
}

// Round 9
// 6548.741 us; speedup vs baseline: 1.7236x; 1.7236x over previous
//
#include <hip/hip_runtime.h>

#define NUM_ITERS 15
#define BB 2
#define NN 2048
#define QQ 256
#define CHUNKS 16          // colsum n-chunks of 128 rows

// ---------------------------------------------------------------------------
// Numerical contract (matches numpy-fp32 golden, verified R8 absmax 0.00195):
//  - no FMA contraction (pragma clang fp contract(off))
//  - GEMM per output element: single fp32 accumulator, strictly ascending k,
//    round(mul) then round(add), final true division by max(sum,1)
//  - row reductions over q=256: numpy pairwise tree (8-acc blocks of 128,
//    fixed combine), replicated exactly (parallelized but same association)
//  - colsum: ascending-n in 16 chunks, combined ascending (only deviation
//    from R8; masked one-hot sums are exact under any grouping)
// ---------------------------------------------------------------------------

// ---------------------------------------------------------------------------
// Fused column sums, chunked: partials p*[c][b][m] over rows n in chunk c.
// Computes masked (act) and unmasked variants in one adj pass.
// ---------------------------------------------------------------------------
__global__ __launch_bounds__(256) void colsum_part(
    const float* __restrict__ adj, const float* __restrict__ act,
    float* __restrict__ pe0, float* __restrict__ pi0,
    float* __restrict__ pe1, float* __restrict__ pi1)
{
#pragma clang fp contract(off)
    const int b = (int)blockIdx.z;
    const int c = (int)blockIdx.y;
    const int m = (int)blockIdx.x * 256 + (int)threadIdx.x;
    const float* src = adj + (size_t)b * NN * NN;
    const float* ab  = act + (size_t)b * NN;
    float se0 = 0.0f, si0 = 0.0f, se1 = 0.0f, si1 = 0.0f;
    const int n0 = c * (NN / CHUNKS);
    for (int n = n0; n < n0 + NN / CHUNKS; ++n) {
        float x = src[(size_t)n * NN + m];
        float e = (x > 0.5f) ? x : 0.0f;
        float v = 1.0f - x;
        float iv = (v > 0.5f) ? v : 0.0f;
        float av = ab[n];
        se1 = se1 + e;
        si1 = si1 + iv;
        se0 = se0 + e * av;
        si0 = si0 + iv * av;
    }
    size_t o = ((size_t)c * BB + b) * NN + m;
    pe0[o] = se0; pi0[o] = si0; pe1[o] = se1; pi1[o] = si1;
}

// Combine partials in ascending chunk order (regrouped ascending-n sum).
__global__ __launch_bounds__(256) void colsum_combine(
    const float* __restrict__ pe0, const float* __restrict__ pi0,
    const float* __restrict__ pe1, const float* __restrict__ pi1,
    float* __restrict__ se0, float* __restrict__ si0,
    float* __restrict__ se1, float* __restrict__ si1)
{
#pragma clang fp contract(off)
    const int i = (int)blockIdx.x * 256 + (int)threadIdx.x;   // 0..BB*NN-1
    float a = 0.0f, bb = 0.0f, cc = 0.0f, dd = 0.0f;
    for (int c = 0; c < CHUNKS; ++c) {
        size_t o = (size_t)c * (BB * NN) + i;
        a  = a  + pe0[o];
        bb = bb + pi0[o];
        cc = cc + pe1[o];
        dd = dd + pi1[o];
    }
    se0[i] = a; si0[i] = bb; se1[i] = cc; si1[i] = dd;
}

// ---------------------------------------------------------------------------
// Fused thresholded GEMM, np-fp32-exact (same per-element chain as R8):
//   C[m][q] = sum_k (thr(adj[k][m]) * act[k]) * hsrc[k][q]
//   mode 0: dst = h_old + C/max(sum,1);  mode 1: dst = C/max(sum,1)
// M-tile 32 x Q-tile 64, BK=32, 256 threads, thread computes 2x4.
// Grid (NN/32, QQ/64, BB) = 512 blocks -> 2 blocks/CU (8 waves/CU).
// ---------------------------------------------------------------------------
__global__ __launch_bounds__(256, 2) void gemm_fused(
    const float* __restrict__ adj,
    const float* __restrict__ hsrc,
    const float* act,
    const float* __restrict__ sums,
    const float* h_old,
    float* __restrict__ dst,
    int mode)
{
#pragma clang fp contract(off)
    __shared__ float Ws[32][34];   // stride 34: b64-aligned, conflict-free
    __shared__ float Hs[32][68];   // stride 68: b128-aligned, conflict-free

    const int b  = (int)blockIdx.z;
    const int m0 = (int)blockIdx.x * 32;
    const int q0 = (int)blockIdx.y * 64;
    const int tid = (int)threadIdx.x;
    const int tm2 = (tid & 15) * 2;
    const int tq  = (tid >> 4) * 4;

    const float* adjb = adj + (size_t)b * NN * NN;
    const float* hb   = hsrc + (size_t)b * NN * QQ;
    const float* ab   = (act != 0) ? (act + (size_t)b * NN) : (const float*)0;

    float acc[2][4];
    for (int i = 0; i < 2; ++i)
        for (int j = 0; j < 4; ++j)
            acc[i][j] = 0.0f;

    for (int k0 = 0; k0 < NN; k0 += 32) {
        // stage Ws (32 rows x 32 cols)
        {
            int idx = tid;
            #pragma unroll
            for (int i = 0; i < 4; ++i) {
                int kk = idx >> 5;
                int mm = idx & 31;
                float x = adjb[(size_t)(k0 + kk) * NN + m0 + mm];
                float wgt;
                if (mode == 0) {
                    wgt = (x > 0.5f) ? x : 0.0f;
                } else {
                    float v = 1.0f - x;
                    wgt = (v > 0.5f) ? v : 0.0f;
                }
                if (ab != 0) wgt = wgt * ab[k0 + kk];
                Ws[kk][mm] = wgt;
                idx += 256;
            }
        }
        // stage Hs (32 rows x 64 cols)
        {
            int idx = tid;
            #pragma unroll
            for (int i = 0; i < 8; ++i) {
                int kk = idx >> 6;
                int qq = idx & 63;
                Hs[kk][qq] = hb[(size_t)(k0 + kk) * QQ + q0 + qq];
                idx += 256;
            }
        }
        __syncthreads();
        #pragma unroll
        for (int kk = 0; kk < 32; ++kk) {
            float a0 = Ws[kk][tm2];
            float a1 = Ws[kk][tm2 + 1];
            float b0 = Hs[kk][tq + 0];
            float b1 = Hs[kk][tq + 1];
            float b2 = Hs[kk][tq + 2];
            float b3 = Hs[kk][tq + 3];
            acc[0][0] = acc[0][0] + a0 * b0; acc[0][1] = acc[0][1] + a0 * b1;
            acc[0][2] = acc[0][2] + a0 * b2; acc[0][3] = acc[0][3] + a0 * b3;
            acc[1][0] = acc[1][0] + a1 * b0; acc[1][1] = acc[1][1] + a1 * b1;
            acc[1][2] = acc[1][2] + a1 * b2; acc[1][3] = acc[1][3] + a1 * b3;
        }
        __syncthreads();
    }

    for (int i = 0; i < 2; ++i) {
        int row = m0 + tm2 + i;
        float s = sums[b * NN + row];
        if (s < 1.0f) s = 1.0f;
        for (int j = 0; j < 4; ++j) {
            int col = q0 + tq + j;
            size_t gi = ((size_t)b * NN + row) * QQ + col;
            float v = acc[i][j] / s;
            if (mode == 0) {
                dst[gi] = h_old[gi] + v;
            } else {
                dst[gi] = v;
            }
        }
    }
}

// ---------------------------------------------------------------------------
// Projection + relu + L2-normalize, np-fp32-exact, in place on h_io.
// Pairwise trees parallelized with IDENTICAL association order:
// 16 lanes compute the 16 r_j partials (ascending stride-8), thread 0 applies
// the fixed combine tree. Block = one row m (256 threads). Grid (NN, BB).
// ---------------------------------------------------------------------------
__global__ __launch_bounds__(256) void project_kernel(
    float* h_io, const float* __restrict__ ieff)
{
#pragma clang fp contract(off)
    __shared__ float sp[256];
    __shared__ float sq[256];
    __shared__ float rs[32];
    __shared__ float sc[2];
    const int b = (int)blockIdx.y;
    const int m = (int)blockIdx.x;
    const int t = (int)threadIdx.x;

    size_t gi = ((size_t)b * NN + m) * QQ + t;
    float hv = h_io[gi];
    float ie = ieff[gi];

    sp[t] = hv * ie;
    sq[t] = ie * ie;
    __syncthreads();
    if (t < 32) {
        const float* a = (t < 16) ? sp : sq;
        int j = t & 7;
        int base = (t & 8) ? 128 : 0;
        float r = a[base + j];
        for (int i = 8; i < 128; i += 8) r = r + a[base + i + j];
        rs[t] = r;
    }
    __syncthreads();
    if (t == 0) {
        float d0 = ((rs[0] + rs[1]) + (rs[2] + rs[3])) + ((rs[4] + rs[5]) + (rs[6] + rs[7]));
        float d1 = ((rs[8] + rs[9]) + (rs[10] + rs[11])) + ((rs[12] + rs[13]) + (rs[14] + rs[15]));
        float dot = d0 + d1;
        float u0 = ((rs[16] + rs[17]) + (rs[18] + rs[19])) + ((rs[20] + rs[21]) + (rs[22] + rs[23]));
        float u1 = ((rs[24] + rs[25]) + (rs[26] + rs[27])) + ((rs[28] + rs[29]) + (rs[30] + rs[31]));
        float un = u0 + u1;
        sc[0] = dot / (un + 1e-12f);
    }
    __syncthreads();
    float c = sc[0];
    float tmp = c * ie;
    float h2 = hv - tmp;
    float r = (h2 > 0.0f) ? h2 : 0.0f;
    sp[t] = r * r;
    __syncthreads();
    if (t < 16) {
        int j = t & 7;
        int base = (t & 8) ? 128 : 0;
        float rr = sp[base + j];
        for (int i = 8; i < 128; i += 8) rr = rr + sp[base + i + j];
        rs[t] = rr;
    }
    __syncthreads();
    if (t == 0) {
        float n0 = ((rs[0] + rs[1]) + (rs[2] + rs[3])) + ((rs[4] + rs[5]) + (rs[6] + rs[7]));
        float n1 = ((rs[8] + rs[9]) + (rs[10] + rs[11])) + ((rs[12] + rs[13]) + (rs[14] + rs[15]));
        float nn = n0 + n1;
        float den = (float)sqrt((double)nn);
        if (den < 1e-8f) den = 1e-8f;
        sc[1] = den;
    }
    __syncthreads();
    h_io[gi] = r / sc[1];
}

// ---------------------------------------------------------------------------
extern "C" void kernel_launch(void* const* d_in, const int* in_sizes, int n_in,
                              void* d_out, int out_size, void* d_ws, size_t ws_size,
                              hipStream_t stream)
{
    const float* h0     = 0;
    const float* adj    = 0;
    const float* act_in = 0;
    for (int i = 0; i < n_in; ++i) {
        if (in_sizes[i] == BB * NN * QQ)      h0     = (const float*)d_in[i];
        else if (in_sizes[i] == BB * NN * NN) adj    = (const float*)d_in[i];
        else if (in_sizes[i] == BB * NN)      act_in = (const float*)d_in[i];
    }
    float* out = (float*)d_out;

    char* ws = (char*)d_ws;
    size_t off = 0;
    float* ieff = (float*)(ws + off); off += (size_t)BB * NN * QQ * 4;      // 4 MB
    float* pe0 = (float*)(ws + off); off += (size_t)CHUNKS * BB * NN * 4;   // 256 KB
    float* pi0 = (float*)(ws + off); off += (size_t)CHUNKS * BB * NN * 4;
    float* pe1 = (float*)(ws + off); off += (size_t)CHUNKS * BB * NN * 4;
    float* pi1 = (float*)(ws + off); off += (size_t)CHUNKS * BB * NN * 4;
    float* sum_e0 = (float*)(ws + off); off += (size_t)BB * NN * 4;
    float* sum_i0 = (float*)(ws + off); off += (size_t)BB * NN * 4;
    float* sum_e1 = (float*)(ws + off); off += (size_t)BB * NN * 4;
    float* sum_i1 = (float*)(ws + off); off += (size_t)BB * NN * 4;

    const size_t slice_sz = (size_t)BB * NN * QQ;

    colsum_part<<<dim3(NN / 256, CHUNKS, BB), 256, 0, stream>>>(
        adj, act_in, pe0, pi0, pe1, pi1);
    colsum_combine<<<dim3(BB * NN / 256), 256, 0, stream>>>(
        pe0, pi0, pe1, pi1, sum_e0, sum_i0, sum_e1, sum_i1);

    for (int it = 0; it < NUM_ITERS; ++it) {
        const float* act = (it == 0) ? act_in : (const float*)0;
        const float* se  = (it == 0) ? sum_e0 : sum_e1;
        const float* si  = (it == 0) ? sum_i0 : sum_i1;
        const float* h_prev = (it == 0) ? h0 : (out + (size_t)(it - 1) * slice_sz);
        float* h_cur = out + (size_t)it * slice_sz;

        // h_cur = h_prev + e_eff   (excite)
        gemm_fused<<<dim3(NN / 32, QQ / 64, BB), 256, 0, stream>>>(
            adj, h_prev, act, se, h_prev, h_cur, 0);
        // ieff from updated h     (inhibit)
        gemm_fused<<<dim3(NN / 32, QQ / 64, BB), 256, 0, stream>>>(
            adj, h_cur, act, si, (const float*)0, ieff, 1);
        // projection + relu + normalize (np-exact), in place
        project_kernel<<<dim3(NN, BB), 256, 0, stream>>>(h_cur, ieff);
    }
}

// Round 10
// 5462.618 us; speedup vs baseline: 2.0663x; 1.1988x over previous
//
#include <hip/hip_runtime.h>

#define NUM_ITERS 15
#define BB 2
#define NN 2048
#define QQ 256
#define CHUNKS 16          // colsum n-chunks of 128 rows

// ---------------------------------------------------------------------------
// Numerical contract (matches numpy-fp32 golden; verified absmax 0.00195 in
// R8/R9 — LOAD-BEARING, do not relax):
//  - no FMA contraction (pragma clang fp contract(off))
//  - GEMM per output element: single fp32 accumulator, strictly ascending k,
//    round(mul) then round(add), final true division by max(sum,1)
//  - row reductions over q=256: numpy pairwise tree (8-acc blocks of 128,
//    fixed combine), association order replicated exactly
//  - colsum: ascending-n in 16 chunks, combined ascending
// ---------------------------------------------------------------------------

__global__ __launch_bounds__(256) void colsum_part(
    const float* __restrict__ adj, const float* __restrict__ act,
    float* __restrict__ pe0, float* __restrict__ pi0,
    float* __restrict__ pe1, float* __restrict__ pi1)
{
#pragma clang fp contract(off)
    const int b = (int)blockIdx.z;
    const int c = (int)blockIdx.y;
    const int m = (int)blockIdx.x * 256 + (int)threadIdx.x;
    const float* src = adj + (size_t)b * NN * NN;
    const float* ab  = act + (size_t)b * NN;
    float se0 = 0.0f, si0 = 0.0f, se1 = 0.0f, si1 = 0.0f;
    const int n0 = c * (NN / CHUNKS);
    for (int n = n0; n < n0 + NN / CHUNKS; ++n) {
        float x = src[(size_t)n * NN + m];
        float e = (x > 0.5f) ? x : 0.0f;
        float v = 1.0f - x;
        float iv = (v > 0.5f) ? v : 0.0f;
        float av = ab[n];
        se1 = se1 + e;
        si1 = si1 + iv;
        se0 = se0 + e * av;
        si0 = si0 + iv * av;
    }
    size_t o = ((size_t)c * BB + b) * NN + m;
    pe0[o] = se0; pi0[o] = si0; pe1[o] = se1; pi1[o] = si1;
}

__global__ __launch_bounds__(256) void colsum_combine(
    const float* __restrict__ pe0, const float* __restrict__ pi0,
    const float* __restrict__ pe1, const float* __restrict__ pi1,
    float* __restrict__ se0, float* __restrict__ si0,
    float* __restrict__ se1, float* __restrict__ si1)
{
#pragma clang fp contract(off)
    const int i = (int)blockIdx.x * 256 + (int)threadIdx.x;   // 0..BB*NN-1
    float a = 0.0f, bb = 0.0f, cc = 0.0f, dd = 0.0f;
    for (int c = 0; c < CHUNKS; ++c) {
        size_t o = (size_t)c * (BB * NN) + i;
        a  = a  + pe0[o];
        bb = bb + pi0[o];
        cc = cc + pe1[o];
        dd = dd + pi1[o];
    }
    se0[i] = a; si0[i] = bb; se1[i] = cc; si1[i] = dd;
}

// ---------------------------------------------------------------------------
// Fused thresholded GEMM, np-fp32-exact per-element chain:
//   C[m][q] = sum_k (thr(adj[k][m]) * act[k]) * hsrc[k][q]   (ascending k)
//   mode 0: dst = h_old + C/max(sum,1);  mode 1: dst = C/max(sum,1)
// Tile M=32 x Q=32, BK=64, 256 threads, thread computes 2x2.
// Grid (NN/32, QQ/32, BB) = 1024 blocks -> 4 blocks/CU (16 waves/CU).
// ---------------------------------------------------------------------------
__global__ __launch_bounds__(256, 4) void gemm_fused(
    const float* __restrict__ adj,
    const float* __restrict__ hsrc,
    const float* act,
    const float* __restrict__ sums,
    const float* h_old,
    float* __restrict__ dst,
    int mode)
{
#pragma clang fp contract(off)
    __shared__ float Ws[64][34];   // row stride 34 floats (8B-aligned, pad)
    __shared__ float Hs[64][34];

    const int b  = (int)blockIdx.z;
    const int m0 = (int)blockIdx.x * 32;
    const int q0 = (int)blockIdx.y * 32;
    const int tid = (int)threadIdx.x;
    const int tm2 = (tid & 15) * 2;
    const int tq2 = (tid >> 4) * 2;

    const float* adjb = adj + (size_t)b * NN * NN;
    const float* hb   = hsrc + (size_t)b * NN * QQ;
    const float* ab   = (act != 0) ? (act + (size_t)b * NN) : (const float*)0;

    float acc00 = 0.0f, acc01 = 0.0f, acc10 = 0.0f, acc11 = 0.0f;

    for (int k0 = 0; k0 < NN; k0 += 64) {
        // stage Ws (64 k-rows x 32 m-cols) and Hs (64 k-rows x 32 q-cols)
        {
            int idx = tid;
            #pragma unroll
            for (int i = 0; i < 8; ++i) {
                int kk = idx >> 5;
                int mm = idx & 31;
                float x = adjb[(size_t)(k0 + kk) * NN + m0 + mm];
                float wgt;
                if (mode == 0) {
                    wgt = (x > 0.5f) ? x : 0.0f;
                } else {
                    float v = 1.0f - x;
                    wgt = (v > 0.5f) ? v : 0.0f;
                }
                if (ab != 0) wgt = wgt * ab[k0 + kk];
                Ws[kk][mm] = wgt;
                Hs[kk][mm] = hb[(size_t)(k0 + kk) * QQ + q0 + mm];
                idx += 256;
            }
        }
        __syncthreads();
        #pragma unroll
        for (int kk = 0; kk < 64; ++kk) {
            float a0 = Ws[kk][tm2];
            float a1 = Ws[kk][tm2 + 1];
            float b0 = Hs[kk][tq2];
            float b1 = Hs[kk][tq2 + 1];
            acc00 = acc00 + a0 * b0; acc01 = acc01 + a0 * b1;
            acc10 = acc10 + a1 * b0; acc11 = acc11 + a1 * b1;
        }
        __syncthreads();
    }

    {
        int row0 = m0 + tm2;
        int row1 = row0 + 1;
        float s0 = sums[b * NN + row0];
        float s1 = sums[b * NN + row1];
        if (s0 < 1.0f) s0 = 1.0f;
        if (s1 < 1.0f) s1 = 1.0f;
        int col0 = q0 + tq2;
        size_t g00 = ((size_t)b * NN + row0) * QQ + col0;
        size_t g10 = ((size_t)b * NN + row1) * QQ + col0;
        float v00 = acc00 / s0;
        float v01 = acc01 / s0;
        float v10 = acc10 / s1;
        float v11 = acc11 / s1;
        if (mode == 0) {
            dst[g00]     = h_old[g00]     + v00;
            dst[g00 + 1] = h_old[g00 + 1] + v01;
            dst[g10]     = h_old[g10]     + v10;
            dst[g10 + 1] = h_old[g10 + 1] + v11;
        } else {
            dst[g00]     = v00;
            dst[g00 + 1] = v01;
            dst[g10]     = v10;
            dst[g10 + 1] = v11;
        }
    }
}

// ---------------------------------------------------------------------------
// Projection + relu + L2-normalize, np-fp32-exact, in place on h_io.
// Pairwise trees parallelized with IDENTICAL association order.
// Block = one row m (256 threads). Grid (NN, BB).
// ---------------------------------------------------------------------------
__global__ __launch_bounds__(256) void project_kernel(
    float* h_io, const float* __restrict__ ieff)
{
#pragma clang fp contract(off)
    __shared__ float sp[256];
    __shared__ float sq[256];
    __shared__ float rs[32];
    __shared__ float sc[2];
    const int b = (int)blockIdx.y;
    const int m = (int)blockIdx.x;
    const int t = (int)threadIdx.x;

    size_t gi = ((size_t)b * NN + m) * QQ + t;
    float hv = h_io[gi];
    float ie = ieff[gi];

    sp[t] = hv * ie;
    sq[t] = ie * ie;
    __syncthreads();
    if (t < 32) {
        const float* a = (t < 16) ? sp : sq;
        int j = t & 7;
        int base = (t & 8) ? 128 : 0;
        float r = a[base + j];
        for (int i = 8; i < 128; i += 8) r = r + a[base + i + j];
        rs[t] = r;
    }
    __syncthreads();
    if (t == 0) {
        float d0 = ((rs[0] + rs[1]) + (rs[2] + rs[3])) + ((rs[4] + rs[5]) + (rs[6] + rs[7]));
        float d1 = ((rs[8] + rs[9]) + (rs[10] + rs[11])) + ((rs[12] + rs[13]) + (rs[14] + rs[15]));
        float dot = d0 + d1;
        float u0 = ((rs[16] + rs[17]) + (rs[18] + rs[19])) + ((rs[20] + rs[21]) + (rs[22] + rs[23]));
        float u1 = ((rs[24] + rs[25]) + (rs[26] + rs[27])) + ((rs[28] + rs[29]) + (rs[30] + rs[31]));
        float un = u0 + u1;
        sc[0] = dot / (un + 1e-12f);
    }
    __syncthreads();
    float c = sc[0];
    float tmp = c * ie;
    float h2 = hv - tmp;
    float r = (h2 > 0.0f) ? h2 : 0.0f;
    sp[t] = r * r;
    __syncthreads();
    if (t < 16) {
        int j = t & 7;
        int base = (t & 8) ? 128 : 0;
        float rr = sp[base + j];
        for (int i = 8; i < 128; i += 8) rr = rr + sp[base + i + j];
        rs[t] = rr;
    }
    __syncthreads();
    if (t == 0) {
        float n0 = ((rs[0] + rs[1]) + (rs[2] + rs[3])) + ((rs[4] + rs[5]) + (rs[6] + rs[7]));
        float n1 = ((rs[8] + rs[9]) + (rs[10] + rs[11])) + ((rs[12] + rs[13]) + (rs[14] + rs[15]));
        float nn = n0 + n1;
        float den = (float)sqrt((double)nn);
        if (den < 1e-8f) den = 1e-8f;
        sc[1] = den;
    }
    __syncthreads();
    h_io[gi] = r / sc[1];
}

// ---------------------------------------------------------------------------
extern "C" void kernel_launch(void* const* d_in, const int* in_sizes, int n_in,
                              void* d_out, int out_size, void* d_ws, size_t ws_size,
                              hipStream_t stream)
{
    const float* h0     = 0;
    const float* adj    = 0;
    const float* act_in = 0;
    for (int i = 0; i < n_in; ++i) {
        if (in_sizes[i] == BB * NN * QQ)      h0     = (const float*)d_in[i];
        else if (in_sizes[i] == BB * NN * NN) adj    = (const float*)d_in[i];
        else if (in_sizes[i] == BB * NN)      act_in = (const float*)d_in[i];
    }
    float* out = (float*)d_out;

    char* ws = (char*)d_ws;
    size_t off = 0;
    float* ieff = (float*)(ws + off); off += (size_t)BB * NN * QQ * 4;      // 4 MB
    float* pe0 = (float*)(ws + off); off += (size_t)CHUNKS * BB * NN * 4;   // 256 KB
    float* pi0 = (float*)(ws + off); off += (size_t)CHUNKS * BB * NN * 4;
    float* pe1 = (float*)(ws + off); off += (size_t)CHUNKS * BB * NN * 4;
    float* pi1 = (float*)(ws + off); off += (size_t)CHUNKS * BB * NN * 4;
    float* sum_e0 = (float*)(ws + off); off += (size_t)BB * NN * 4;
    float* sum_i0 = (float*)(ws + off); off += (size_t)BB * NN * 4;
    float* sum_e1 = (float*)(ws + off); off += (size_t)BB * NN * 4;
    float* sum_i1 = (float*)(ws + off); off += (size_t)BB * NN * 4;

    const size_t slice_sz = (size_t)BB * NN * QQ;

    colsum_part<<<dim3(NN / 256, CHUNKS, BB), 256, 0, stream>>>(
        adj, act_in, pe0, pi0, pe1, pi1);
    colsum_combine<<<dim3(BB * NN / 256), 256, 0, stream>>>(
        pe0, pi0, pe1, pi1, sum_e0, sum_i0, sum_e1, sum_i1);

    for (int it = 0; it < NUM_ITERS; ++it) {
        const float* act = (it == 0) ? act_in : (const float*)0;
        const float* se  = (it == 0) ? sum_e0 : sum_e1;
        const float* si  = (it == 0) ? sum_i0 : sum_i1;
        const float* h_prev = (it == 0) ? h0 : (out + (size_t)(it - 1) * slice_sz);
        float* h_cur = out + (size_t)it * slice_sz;

        // h_cur = h_prev + e_eff   (excite)
        gemm_fused<<<dim3(NN / 32, QQ / 32, BB), 256, 0, stream>>>(
            adj, h_prev, act, se, h_prev, h_cur, 0);
        // ieff from updated h     (inhibit)
        gemm_fused<<<dim3(NN / 32, QQ / 32, BB), 256, 0, stream>>>(
            adj, h_cur, act, si, (const float*)0, ieff, 1);
        // projection + relu + normalize (np-exact), in place
        project_kernel<<<dim3(NN, BB), 256, 0, stream>>>(h_cur, ieff);
    }
}